// Round 6
// baseline (122.192 us; speedup 1.0000x reference)
//
#include <hip/hip_runtime.h>
#include <math.h>

// CRF loss: B=256, L=256, T=50. ONE WAVE (64 threads) per batch element,
// barrier-free scan. lane = "to" tag (>=50 pad).
//
// Exp-domain recurrence (R4): exp2(A[f]+t2[f][to]) = exp2(A[f]) * E2[f][to],
// E2 constant in 50 VGPRs -> per step: 1 exp2/lane + 50-term readlane/FMA dot.
//
// R6 changes (stall removal, not work removal):
//  1. Readlanes batched in chunks of 10, software-pipelined against the FMA
//     chunks -> the VALU-writes-SGPR -> VALU-reads-SGPR wait-state hazard
//     (paid 50x/step when rl,fma alternate back-to-back) is hidden.
//  2. Deferred renorm: c = readlane(A,0) of the *previous* step is subtracted
//     in the tail (folded into e-c, computed during the dot product) instead
//     of on the exp2 input path. One un-renormalized step keeps |A| <~ 104
//     log2-units -> exp2/fp32 safe.
//   Invariant: alpha_l / ln2 = A + S after step l.

#define TAGS 50
#define LEN 256
#define INV_LN2 1.4426950408889634f
#define LN2 0.6931471805599453f
#define CH 10            // chunk size (5 chunks of 10 = 50 from-terms)

#if __has_builtin(__builtin_amdgcn_exp2f)
#define EXP2F(x) __builtin_amdgcn_exp2f(x)
#else
#define EXP2F(x) exp2f(x)
#endif
#if __has_builtin(__builtin_amdgcn_logf)
#define LOG2F(x) __builtin_amdgcn_logf(x)
#else
#define LOG2F(x) log2f(x)
#endif

__device__ __forceinline__ float readlane_f(float v, int srclane) {
  return __builtin_bit_cast(float,
      __builtin_amdgcn_readlane(__builtin_bit_cast(int, v), srclane));
}

__global__ __launch_bounds__(64) void crf_fwd_kernel(
    const float* __restrict__ feats,   // (B, L, T)
    const float* __restrict__ trans,   // (T, T)
    const int*   __restrict__ tags,    // (B, L)
    const int*   __restrict__ mask,    // (B, L)
    float*       __restrict__ out)     // (B,)
{
  const int b    = blockIdx.x;
  const int lane = threadIdx.x;                       // "to" tag (>=50 pad)
  const int toc  = lane < TAGS ? lane : (TAGS - 1);

  __shared__ __align__(16) float feats_lds[LEN * TAGS]; // emits, prescaled by 1/ln2
  __shared__ int mask_lds[LEN];

  const float* fb = feats + (size_t)b * (LEN * TAGS);
  const int*   tb = tags + b * LEN;
  const int*   mb = mask + b * LEN;

  // Tags for gold score into registers first (latency overlaps the preload).
  int tg_c[4], tg_p[4];
#pragma unroll
  for (int k = 0; k < 4; ++k) {
    const int p = lane + 64 * k;
    tg_c[k] = tb[p];
    tg_p[k] = (p >= 1) ? tb[p - 1] : 0;
  }

  // ---- Bulk preload: feats[b] (prescaled) + mask[b] ----
  {
    const float4* fv = (const float4*)fb;             // 3200 float4
    for (int i = lane; i < (LEN * TAGS) / 4; i += 64) {
      float4 v = fv[i];
      v.x *= INV_LN2; v.y *= INV_LN2; v.z *= INV_LN2; v.w *= INV_LN2;
      *(float4*)&feats_lds[i * 4] = v;
    }
    for (int i = lane; i < LEN; i += 64) mask_lds[i] = mb[i];
  }

  // Constant exp-domain trans column: E2[f] = exp2(trans[f][toc]/ln2).
  float E2[TAGS];
#pragma unroll
  for (int f = 0; f < TAGS; ++f)
    E2[f] = EXP2F(trans[f * TAGS + toc] * INV_LN2);

  __syncthreads();                                    // single wave: just a waitcnt

  // Init: A = emit0/ln2 (bounded; no renorm needed), S = 0.
  float A = feats_lds[toc];
  float S = 0.0f;

  float e_nxt = feats_lds[TAGS + toc];
  int   m_nxt = mask_lds[1];

  for (int l = 1; l < LEN; ++l) {
    const float e_cur = e_nxt;
    const int   m_cur = m_nxt;
    const int   ln = (l + 1 < LEN) ? (l + 1) : (LEN - 1);
    e_nxt = feats_lds[ln * TAGS + toc];
    m_nxt = mask_lds[ln];

    const float c  = readlane_f(A, 0);                // prev-step renorm, off exp2 path
    const float w  = EXP2F(A);                        // |A| <= ~104: safe
    const float ec = e_cur - c;                       // folded tail constant
    const float Ac = A - c;                           // masked-path value

    float acc[4] = {0.0f, 0.0f, 0.0f, 0.0f};
    float buf[2][CH];
#pragma unroll
    for (int j = 0; j < CH; ++j) buf[0][j] = readlane_f(w, j);
#pragma unroll
    for (int ch = 0; ch < 5; ++ch) {
      if (ch < 4) {
#pragma unroll
        for (int j = 0; j < CH; ++j)
          buf[(ch + 1) & 1][j] = readlane_f(w, (ch + 1) * CH + j);
      }
#pragma unroll
      for (int j = 0; j < CH; ++j)
        acc[j & 3] = fmaf(buf[ch & 1][j], E2[ch * CH + j], acc[j & 3]);
    }
    const float p = (acc[0] + acc[1]) + (acc[2] + acc[3]);   // > 0
    const float raw = LOG2F(p) + ec;
    A = (m_cur > 0) ? raw : Ac;                       // masked: alpha unchanged
    S += c;
  }

  if (lane >= TAGS) A = -INFINITY;                    // kill pads for final LSE

  // ---- Final logsumexp over A ----
  float mx = A;
#pragma unroll
  for (int off = 32; off; off >>= 1) mx = fmaxf(mx, __shfl_xor(mx, off, 64));
  float sum = EXP2F(A - mx);
#pragma unroll
  for (int off = 32; off; off >>= 1) sum += __shfl_xor(sum, off, 64);

  // ---- Gold score: lane handles positions lane, lane+64, lane+128, lane+192 ----
  float gp = 0.0f;
#pragma unroll
  for (int k = 0; k < 4; ++k) {
    const int p = lane + 64 * k;
    if (mask_lds[p] > 0) {
      float v = feats_lds[p * TAGS + tg_c[k]] * LN2;  // un-prescale
      if (p >= 1) v += trans[tg_p[k] * TAGS + tg_c[k]];
      gp += v;
    }
  }
#pragma unroll
  for (int off = 32; off; off >>= 1) gp += __shfl_xor(gp, off, 64);

  if (lane == 0) {
    const float all_path = LN2 * (S + mx + LOG2F(sum));
    out[b] = all_path - gp;
  }
}

extern "C" void kernel_launch(void* const* d_in, const int* in_sizes, int n_in,
                              void* d_out, int out_size, void* d_ws, size_t ws_size,
                              hipStream_t stream) {
  const float* feats = (const float*)d_in[0];
  const float* trans = (const float*)d_in[1];
  const int*   tags  = (const int*)d_in[2];
  const int*   mask  = (const int*)d_in[3];
  float* out = (float*)d_out;

  const int B = out_size;  // 256
  crf_fwd_kernel<<<B, 64, 0, stream>>>(feats, trans, tags, mask, out);
}